// Round 1
// baseline (73157.001 us; speedup 1.0000x reference)
//
#include <hip/hip_runtime.h>
#include <hip/hip_bf16.h>
#include <cstddef>

// Problem constants (from setup_inputs)
#define BB 32
#define TT 2048
#define DD 64
#define HH 256
#define OO 32
#define G4H 1024  // 4*H

// Output layout (floats): out [B,T,O] | h_n [2,B,H] | c_n [2,B,H]
#define OUT_ELEMS   (BB * TT * OO)      // 2097152
#define HN_OFF      OUT_ELEMS           // 2097152
#define CN_OFF      (HN_OFF + 2*BB*HH)  // 2113536

// Workspace layout (float offsets)
#define OFF_Y0      ((size_t)0)                       // 16777216 floats
#define OFF_Y1      ((size_t)16777216)                // 16777216 floats
#define OFF_WIH0T   ((size_t)33554432)                // 65536
#define OFF_WHH0T   (OFF_WIH0T + 65536)               // 262144
#define OFF_WIH1T   (OFF_WHH0T + 262144)              // 262144
#define OFF_WHH1T   (OFF_WIH1T + 262144)              // 262144
#define OFF_WD0T    (OFF_WHH1T + 262144)              // 65536
#define OFF_WD1T    (OFF_WD0T + 65536)                // 65536
#define OFF_WOUTT   (OFF_WD1T + 65536)                // 8192

__device__ __forceinline__ float sigmoidf_(float v) {
    return 1.0f / (1.0f + __expf(-v));
}

// ---------------------------------------------------------------------------
// Prep: build chunked-transposed weights.
// For W [G=1024 rows][K cols]: dst float4 index [k4*1024 + g], component j =
// W[g, 4*k4+j].  Head weights get a plain transpose.
// ---------------------------------------------------------------------------
__global__ void prep_weights(const float* __restrict__ Wih0,
                             const float* __restrict__ Whh0,
                             const float* __restrict__ Wih1,
                             const float* __restrict__ Whh1,
                             const float* __restrict__ Wd0,
                             const float* __restrict__ Wd1,
                             const float* __restrict__ Wout,
                             float* __restrict__ ws) {
    int i = blockIdx.x * blockDim.x + threadIdx.x;
    // chunked transpose for [1024][K] matrices
    // e: j = e&3, q = e>>2, g = q&1023, k4 = q>>10 ; src[g*K + 4*k4 + j]
    if (i < 65536) {  // Wih0, K=64
        int e = i, j = e & 3, q = e >> 2, g = q & 1023, k4 = q >> 10;
        ws[OFF_WIH0T + e] = Wih0[g * 64 + (k4 * 4 + j)];
        return;
    }
    i -= 65536;
    if (i < 262144) {  // Whh0, K=256
        int e = i, j = e & 3, q = e >> 2, g = q & 1023, k4 = q >> 10;
        ws[OFF_WHH0T + e] = Whh0[g * 256 + (k4 * 4 + j)];
        return;
    }
    i -= 262144;
    if (i < 262144) {  // Wih1, K=256
        int e = i, j = e & 3, q = e >> 2, g = q & 1023, k4 = q >> 10;
        ws[OFF_WIH1T + e] = Wih1[g * 256 + (k4 * 4 + j)];
        return;
    }
    i -= 262144;
    if (i < 262144) {  // Whh1, K=256
        int e = i, j = e & 3, q = e >> 2, g = q & 1023, k4 = q >> 10;
        ws[OFF_WHH1T + e] = Whh1[g * 256 + (k4 * 4 + j)];
        return;
    }
    i -= 262144;
    if (i < 65536) {  // Wd0 plain T: dst[h*256+o] = src[o*256+h]
        int e = i, o = e & 255, h = e >> 8;
        ws[OFF_WD0T + e] = Wd0[o * 256 + h];
        return;
    }
    i -= 65536;
    if (i < 65536) {  // Wd1
        int e = i, o = e & 255, h = e >> 8;
        ws[OFF_WD1T + e] = Wd1[o * 256 + h];
        return;
    }
    i -= 65536;
    if (i < 8192) {  // Wout [32][256] -> dst[h*32+o] = src[o*256+h]
        int e = i, o = e & 31, h = e >> 5;
        ws[OFF_WOUTT + e] = Wout[o * 256 + h];
        return;
    }
}

// ---------------------------------------------------------------------------
// LSTM layer: one block per batch element, 1024 threads = one per gate row.
// h, x staged in LDS; weights streamed (coalesced, chunked-T) from L2.
// ---------------------------------------------------------------------------
template <int D>
__global__ __launch_bounds__(1024) void lstm_layer(
    const float* __restrict__ x,      // [B,T,D]
    const float* __restrict__ h0,     // [B,H]
    const float* __restrict__ c0,     // [B,H]
    const float4* __restrict__ WihT4, // [D/4][1024] float4
    const float4* __restrict__ WhhT4, // [H/4][1024] float4
    const float* __restrict__ b_ih,   // [4H]
    const float* __restrict__ b_hh,   // [4H]
    float* __restrict__ y,            // [B,T,H]
    float* __restrict__ hT,           // [B,H]
    float* __restrict__ cT)           // [B,H]
{
    __shared__ __align__(16) float h_lds[HH];
    __shared__ __align__(16) float x_lds[D];
    __shared__ float gate_lds[G4H];

    const int b = blockIdx.x;
    const int g = threadIdx.x;

    if (g < HH) h_lds[g] = h0[b * HH + g];
    float c = (g < HH) ? c0[b * HH + g] : 0.0f;
    const float bias = b_ih[g] + b_hh[g];

    const float4* xf4 = (const float4*)x_lds;
    const float4* hf4 = (const float4*)h_lds;
    __syncthreads();

    for (int t = 0; t < TT; ++t) {
        // stage x_t
        if (g < D) x_lds[g] = x[((size_t)b * TT + t) * D + g];
        __syncthreads();

        float acc = bias;
        #pragma unroll
        for (int k = 0; k < D / 4; ++k) {
            float4 w = WihT4[k * G4H + g];
            float4 v = xf4[k];
            acc += w.x * v.x + w.y * v.y + w.z * v.z + w.w * v.w;
        }
        #pragma unroll 8
        for (int k = 0; k < HH / 4; ++k) {
            float4 w = WhhT4[k * G4H + g];
            float4 v = hf4[k];
            acc += w.x * v.x + w.y * v.y + w.z * v.z + w.w * v.w;
        }
        gate_lds[g] = acc;
        __syncthreads();

        if (g < HH) {
            float iv = sigmoidf_(gate_lds[g]);
            float fv = sigmoidf_(gate_lds[g + 256]);
            float gv = tanhf(gate_lds[g + 512]);
            float ov = sigmoidf_(gate_lds[g + 768]);
            c = fv * c + iv * gv;
            float h = ov * tanhf(c);
            h_lds[g] = h;
            y[((size_t)b * TT + t) * HH + g] = h;
        }
        __syncthreads();
    }

    if (g < HH) {
        hT[b * HH + g] = h_lds[g];
        cT[b * HH + g] = c;
    }
}

// ---------------------------------------------------------------------------
// Fused dense head: per 16-row tile, relu(L0) -> relu(L1) -> Lout, ping-pong
// LDS, no global intermediates.
// ---------------------------------------------------------------------------
__global__ __launch_bounds__(256) void head_kernel(
    const float* __restrict__ y1,     // [B*T, 256]
    const float* __restrict__ Wd0T,   // [256][256] (h-major)
    const float* __restrict__ bd0,
    const float* __restrict__ Wd1T,   // [256][256]
    const float* __restrict__ bd1,
    const float* __restrict__ WoutT,  // [256][32]
    const float* __restrict__ bout,
    float* __restrict__ out)          // [B*T, 32]
{
    __shared__ float buf0[16][256];
    __shared__ float buf1[16][256];
    const int row0 = blockIdx.x * 16;
    const int tid = threadIdx.x;

    // load 16x256 tile (coalesced)
    #pragma unroll
    for (int i = 0; i < 16; ++i)
        buf0[i][tid] = y1[(size_t)(row0 + i) * 256 + tid];
    __syncthreads();

    // stage 1: buf0 -> buf1 (column tid)
    {
        float acc[16];
        float bv = bd0[tid];
        #pragma unroll
        for (int r = 0; r < 16; ++r) acc[r] = bv;
        for (int h = 0; h < 256; ++h) {
            float w = Wd0T[h * 256 + tid];
            #pragma unroll
            for (int r = 0; r < 16; ++r) acc[r] += w * buf0[r][h];
        }
        __syncthreads();  // everyone done reading buf0? (no: buf1 write is safe, buf0 untouched)
        #pragma unroll
        for (int r = 0; r < 16; ++r) buf1[r][tid] = fmaxf(acc[r], 0.0f);
    }
    __syncthreads();

    // stage 2: buf1 -> buf0
    {
        float acc[16];
        float bv = bd1[tid];
        #pragma unroll
        for (int r = 0; r < 16; ++r) acc[r] = bv;
        for (int h = 0; h < 256; ++h) {
            float w = Wd1T[h * 256 + tid];
            #pragma unroll
            for (int r = 0; r < 16; ++r) acc[r] += w * buf1[r][h];
        }
        __syncthreads();  // all reads of buf0 from stage1 load are done; safe to overwrite
        #pragma unroll
        for (int r = 0; r < 16; ++r) buf0[r][tid] = fmaxf(acc[r], 0.0f);
    }
    __syncthreads();

    // stage 3: buf0 -> out.  tid = rr*32 + o, each thread 2 rows.
    {
        const int o = tid & 31;
        const int rr = tid >> 5;
        float a0 = bout[o], a1 = bout[o];
        for (int h = 0; h < 256; ++h) {
            float w = WoutT[h * 32 + o];
            a0 += w * buf0[rr * 2 + 0][h];
            a1 += w * buf0[rr * 2 + 1][h];
        }
        out[(size_t)(row0 + rr * 2 + 0) * 32 + o] = a0;
        out[(size_t)(row0 + rr * 2 + 1) * 32 + o] = a1;
    }
}

// ---------------------------------------------------------------------------
extern "C" void kernel_launch(void* const* d_in, const int* in_sizes, int n_in,
                              void* d_out, int out_size, void* d_ws, size_t ws_size,
                              hipStream_t stream) {
    const float* x     = (const float*)d_in[0];
    const float* h0    = (const float*)d_in[1];   // [2,B,H]
    const float* c0    = (const float*)d_in[2];
    const float* Wih0  = (const float*)d_in[3];
    const float* Whh0  = (const float*)d_in[4];
    const float* bih0  = (const float*)d_in[5];
    const float* bhh0  = (const float*)d_in[6];
    const float* Wih1  = (const float*)d_in[7];
    const float* Whh1  = (const float*)d_in[8];
    const float* bih1  = (const float*)d_in[9];
    const float* bhh1  = (const float*)d_in[10];
    const float* Wd0   = (const float*)d_in[11];
    const float* bd0   = (const float*)d_in[12];
    const float* Wd1   = (const float*)d_in[13];
    const float* bd1   = (const float*)d_in[14];
    const float* Wout  = (const float*)d_in[15];
    const float* bout  = (const float*)d_in[16];

    float* out = (float*)d_out;
    float* wsf = (float*)d_ws;

    // 1) weight transposes (991232 elements)
    prep_weights<<<3872, 256, 0, stream>>>(Wih0, Whh0, Wih1, Whh1, Wd0, Wd1, Wout, wsf);

    // 2) layer 0
    lstm_layer<DD><<<BB, 1024, 0, stream>>>(
        x, h0, c0,
        (const float4*)(wsf + OFF_WIH0T), (const float4*)(wsf + OFF_WHH0T),
        bih0, bhh0,
        wsf + OFF_Y0, out + HN_OFF, out + CN_OFF);

    // 3) layer 1 (input = y0)
    lstm_layer<HH><<<BB, 1024, 0, stream>>>(
        wsf + OFF_Y0, h0 + BB * HH, c0 + BB * HH,
        (const float4*)(wsf + OFF_WIH1T), (const float4*)(wsf + OFF_WHH1T),
        bih1, bhh1,
        wsf + OFF_Y1, out + HN_OFF + BB * HH, out + CN_OFF + BB * HH);

    // 4) fused dense head
    head_kernel<<<(BB * TT) / 16, 256, 0, stream>>>(
        wsf + OFF_Y1,
        wsf + OFF_WD0T, bd0,
        wsf + OFF_WD1T, bd1,
        wsf + OFF_WOUTT, bout,
        out);
}

// Round 2
// 13753.896 us; speedup vs baseline: 5.3190x; 5.3190x over previous
//
#include <hip/hip_runtime.h>
#include <hip/hip_bf16.h>
#include <cstddef>
#include <cstdint>

// B=32, T=2048, D=64, H=256, O=32, 4H=1024
#define BB 32
#define TT 2048
#define DD 64
#define HH 256
#define OO 32

#define OUT_ELEMS (BB*TT*OO)
#define HN_OFF OUT_ELEMS
#define CN_OFF (HN_OFF + 2*BB*HH)

// ---------------- workspace byte offsets ----------------
// x_bf16 [32][2048][64] bf16
#define O_XBF   ((size_t)0)
// h0buf [2049][32][256] bf16  (h state of layer0 before step t)
#define O_H0    (O_XBF + (size_t)8388608)
// xh1buf [2049][32][512] bf16 (cols 0:256 = y0[t] from layer0, 256:512 = h1 before step t)
#define O_XH1   (O_H0 + (size_t)33570816)
// Wcat0 [1024][320] bf16 (cols 0:64 Wih0 | 64:320 Whh0)
#define O_WC0   (O_XH1 + (size_t)67141632)
// Wcat1 [1024][512] bf16 (cols 0:256 Wih1 | 256:512 Whh1)
#define O_WC1   (O_WC0 + 655360)
#define O_B0    (O_WC1 + 1048576)   // bias0 [1024] f32
#define O_B1    (O_B0 + 4096)       // bias1 [1024] f32
#define O_WD0T  (O_B1 + 4096)       // [256][256] f32, dst[h*256+o]=Wd0[o*256+h]
#define O_WD1T  (O_WD0T + 262144)
#define O_WOUT  (O_WD1T + 262144)   // [256][32] f32
#define O_DONE0 (O_WOUT + 32768)    // int[2048]
#define O_DONE1 (O_DONE0 + 8192)    // int[2048]

typedef short short8 __attribute__((ext_vector_type(8)));
typedef float f32x4 __attribute__((ext_vector_type(4)));

__device__ __forceinline__ float sigm_(float x){ return 1.0f/(1.0f+__expf(-x)); }
__device__ __forceinline__ float tanhf_(float x){
    float xc = fminf(fmaxf(x, -15.0f), 15.0f);
    float e = __expf(2.0f*xc);
    return (e-1.0f)/(e+1.0f);
}
__device__ __forceinline__ unsigned short f2bf(float f){
    __hip_bfloat16 h = __float2bfloat16(f);
    return *reinterpret_cast<unsigned short*>(&h);
}

// ---------------------------------------------------------------------------
// Prep: bf16 conversions, weight concat, bias sums, head-weight transposes,
// h-state inits, done-counter zeroing.  Flat element index over all ranges.
// total = 4194304+327680+524288+1024+1024+8192+8192+65536+65536+8192+4096
//       = 5208064 = 20344 * 256
// ---------------------------------------------------------------------------
__global__ void prep_kernel(const float* __restrict__ x, const float* __restrict__ h0,
    const float* __restrict__ Wih0, const float* __restrict__ Whh0,
    const float* __restrict__ bih0, const float* __restrict__ bhh0,
    const float* __restrict__ Wih1, const float* __restrict__ Whh1,
    const float* __restrict__ bih1, const float* __restrict__ bhh1,
    const float* __restrict__ Wd0, const float* __restrict__ Wd1,
    const float* __restrict__ Wout, char* __restrict__ ws)
{
    int i = blockIdx.x*256 + threadIdx.x;
    if (i < 4194304) { ((unsigned short*)(ws+O_XBF))[i] = f2bf(x[i]); return; }
    i -= 4194304;
    if (i < 327680) {
        int g = i/320, k = i - g*320;
        float v = (k < 64) ? Wih0[g*64 + k] : Whh0[g*256 + (k-64)];
        ((unsigned short*)(ws+O_WC0))[i] = f2bf(v); return;
    }
    i -= 327680;
    if (i < 524288) {
        int g = i >> 9, k = i & 511;
        float v = (k < 256) ? Wih1[g*256 + k] : Whh1[g*256 + (k-256)];
        ((unsigned short*)(ws+O_WC1))[i] = f2bf(v); return;
    }
    i -= 524288;
    if (i < 1024) { ((float*)(ws+O_B0))[i] = bih0[i] + bhh0[i]; return; }
    i -= 1024;
    if (i < 1024) { ((float*)(ws+O_B1))[i] = bih1[i] + bhh1[i]; return; }
    i -= 1024;
    if (i < 8192) { ((unsigned short*)(ws+O_H0))[i] = f2bf(h0[i]); return; }  // h0buf[0][b][h]
    i -= 8192;
    if (i < 8192) {  // xh1buf[0][b][256+h] = h0[1][b][h]
        int b = i >> 8, h = i & 255;
        ((unsigned short*)(ws+O_XH1))[b*512 + 256 + h] = f2bf(h0[8192 + i]); return;
    }
    i -= 8192;
    if (i < 65536) { int o = i & 255, h = i >> 8; ((float*)(ws+O_WD0T))[i] = Wd0[o*256 + h]; return; }
    i -= 65536;
    if (i < 65536) { int o = i & 255, h = i >> 8; ((float*)(ws+O_WD1T))[i] = Wd1[o*256 + h]; return; }
    i -= 65536;
    if (i < 8192) { int o = i & 31, h = i >> 5; ((float*)(ws+O_WOUT))[i] = Wout[o*256 + h]; return; }
    i -= 8192;
    if (i < 4096) { ((int*)(ws+O_DONE0))[i] = 0; return; }  // covers DONE0+DONE1 (contiguous)
}

// ---------------------------------------------------------------------------
// Cross-block sync helpers (agent scope; counters at LLC; capped spin so a
// bug fails validation instead of hanging the harness).
// ---------------------------------------------------------------------------
__device__ __forceinline__ void spin_done(int* p){
    int it = 0;
    while (__hip_atomic_load(p, __ATOMIC_RELAXED, __HIP_MEMORY_SCOPE_AGENT) < 16) {
        __builtin_amdgcn_s_sleep(2);
        if (++it > (1<<20)) break;   // safety escape
    }
    __builtin_amdgcn_fence(__ATOMIC_ACQUIRE, "agent");
}

// ---------------------------------------------------------------------------
// Persistent LSTM layer body.  16 blocks per layer, 512 threads (8 waves).
// Wave w: gate group gg=w&3 (i/f/g/o), batch half bh=w>>2.
// Block j owns h-slice [16j,16j+16): gate rows {16j+256q}.
// Weights stay in VGPRs (A-fragments) for all 2048 steps.
// mfma_f32_16x16x32_bf16: A lane l -> A[row=l&15][k=(l>>4)*8+j];
//                         B lane l -> B[k=(l>>4)*8+j][col=l&15];
//                         D lane l -> D[row=(l>>4)*4+r][col=l&15].
// ---------------------------------------------------------------------------
template<int L>
__device__ void lstm_body(int j, int tid, char* ws,
                          const float* __restrict__ c0_in,
                          float* __restrict__ out,
                          float (*Glds)[32][17])
{
    constexpr int KK  = L ? 512 : 320;  // layer0: 64 x + 256 h ; layer1: 256 y0 + 256 h1
    constexpr int NKT = KK / 32;
    const unsigned short* W   = (const unsigned short*)(ws + (L ? O_WC1 : O_WC0));
    const float* bias         = (const float*)(ws + (L ? O_B1 : O_B0));
    const unsigned short* xbf = (const unsigned short*)(ws + O_XBF);
    unsigned short* h0buf     = (unsigned short*)(ws + O_H0);
    unsigned short* xh1buf    = (unsigned short*)(ws + O_XH1);
    int* done0 = (int*)(ws + O_DONE0);
    int* done1 = (int*)(ws + O_DONE1);

    const int wv = tid >> 6, lane = tid & 63;
    const int gg = wv & 3, bh = wv >> 2;
    const int lrow = lane & 15;
    const int koff = (lane >> 4) * 8;
    const int arow = 256*gg + 16*j + lrow;
    const int fb   = bh*16 + lrow;        // batch index this lane's B-frag serves

    // --- preload weight A-fragments into registers (persist across steps) ---
    short8 afr[NKT];
#pragma unroll
    for (int kk = 0; kk < NKT; ++kk)
        afr[kk] = *(const short8*)(W + (size_t)arow*KK + 32*kk + koff);

    // --- combine-phase identity: thread tid owns (h=tid&15, b=tid>>4) ---
    const int ch = tid & 15;
    const int cb = tid >> 4;
    const int hg = 16*j + ch;
    float c = c0_in[(size_t)L*8192 + cb*256 + hg];
    const float b_i = bias[hg], b_f = bias[256+hg], b_g = bias[512+hg], b_o = bias[768+hg];
    float h_last = 0.0f;

    for (int t = 0; t < TT; ++t) {
        // acquire: inputs for this step
        if (L == 0) { if (t > 0) spin_done(done0 + (t-1)); }
        else        { spin_done(done0 + t); if (t > 0) spin_done(done1 + (t-1)); }

        f32x4 acc = {0.f, 0.f, 0.f, 0.f};
        if (L == 0) {
            const unsigned short* xb = xbf  + ((size_t)fb*TT + t)*64 + koff;
            const unsigned short* hb = h0buf + (size_t)t*8192 + fb*256 + koff;
#pragma unroll
            for (int kk = 0; kk < 2; ++kk)
                acc = __builtin_amdgcn_mfma_f32_16x16x32_bf16(afr[kk],
                        *(const short8*)(xb + 32*kk), acc, 0, 0, 0);
#pragma unroll
            for (int kk = 0; kk < 8; ++kk)
                acc = __builtin_amdgcn_mfma_f32_16x16x32_bf16(afr[2+kk],
                        *(const short8*)(hb + 32*kk), acc, 0, 0, 0);
        } else {
            const unsigned short* xh = xh1buf + (size_t)t*16384 + fb*512 + koff;
#pragma unroll
            for (int kk = 0; kk < 16; ++kk)
                acc = __builtin_amdgcn_mfma_f32_16x16x32_bf16(afr[kk],
                        *(const short8*)(xh + 32*kk), acc, 0, 0, 0);
        }

        // D -> LDS: Glds[gate][b][h-sub], padded to 17 to avoid bank conflicts
        {
            const int n = lane & 15, m4 = (lane >> 4) * 4;
#pragma unroll
            for (int r = 0; r < 4; ++r)
                Glds[gg][bh*16 + n][m4 + r] = acc[r];
        }
        __syncthreads();

        // gate combine (all 512 threads, one (h,b) pair each)
        float gi = Glds[0][cb][ch] + b_i;
        float gf = Glds[1][cb][ch] + b_f;
        float gc = Glds[2][cb][ch] + b_g;
        float go = Glds[3][cb][ch] + b_o;
        float iv = sigm_(gi), fv = sigm_(gf), gv = tanhf_(gc), ov = sigm_(go);
        c = fv*c + iv*gv;
        float hn = ov * tanhf_(c);
        h_last = hn;

        // broadcast h (bf16) with agent-scope stores; pack 2 per dword
        unsigned int us = f2bf(hn);
        unsigned int other = __shfl_xor(us, 1, 64);
        unsigned int word = us | (other << 16);
        if ((tid & 1) == 0) {
            if (L == 0) {
                size_t e0 = (size_t)(t+1)*8192 + (size_t)cb*256 + hg;
                __hip_atomic_store((unsigned int*)(h0buf + e0), word,
                                   __ATOMIC_RELAXED, __HIP_MEMORY_SCOPE_AGENT);
                size_t e1 = (size_t)t*16384 + (size_t)cb*512 + hg;   // y0[t]
                __hip_atomic_store((unsigned int*)(xh1buf + e1), word,
                                   __ATOMIC_RELAXED, __HIP_MEMORY_SCOPE_AGENT);
            } else {
                size_t e2 = (size_t)(t+1)*16384 + (size_t)cb*512 + 256 + hg;  // h1 & y1[t]
                __hip_atomic_store((unsigned int*)(xh1buf + e2), word,
                                   __ATOMIC_RELAXED, __HIP_MEMORY_SCOPE_AGENT);
            }
        }
        __syncthreads();   // all stores retired (barrier drains vmcnt) + Glds reads done
        if (tid == 0)
            __hip_atomic_fetch_add((L ? done1 : done0) + t, 1,
                                   __ATOMIC_RELEASE, __HIP_MEMORY_SCOPE_AGENT);
    }

    // epilogue: h_n / c_n (f32)
    out[HN_OFF + (size_t)L*8192 + cb*256 + hg] = h_last;
    out[CN_OFF + (size_t)L*8192 + cb*256 + hg] = c;
}

__global__ __launch_bounds__(512, 1) void lstm_fused(char* ws,
                                                     const float* __restrict__ c0_in,
                                                     float* __restrict__ out)
{
    __shared__ float Glds[4][32][17];
    const int blk = blockIdx.x, tid = threadIdx.x;
    if (blk < 16) lstm_body<0>(blk,      tid, ws, c0_in, out, Glds);
    else          lstm_body<1>(blk - 16, tid, ws, c0_in, out, Glds);
}

// ---------------------------------------------------------------------------
// Fused dense head (reads y1 as bf16 out of xh1buf h-halves).
// ---------------------------------------------------------------------------
__global__ __launch_bounds__(256) void head_kernel(const char* __restrict__ ws,
    const float* __restrict__ bd0, const float* __restrict__ bd1,
    const float* __restrict__ bout, float* __restrict__ out)
{
    const __hip_bfloat16* xh1 = (const __hip_bfloat16*)(ws + O_XH1);
    const float* Wd0T  = (const float*)(ws + O_WD0T);
    const float* Wd1T  = (const float*)(ws + O_WD1T);
    const float* WoutT = (const float*)(ws + O_WOUT);

    __shared__ float buf0[16][256];
    __shared__ float buf1[16][256];
    const int row0 = blockIdx.x * 16;
    const int tid = threadIdx.x;

#pragma unroll
    for (int i = 0; i < 16; ++i) {
        int r = row0 + i;
        int b = r >> 11, t = r & 2047;
        buf0[i][tid] = __bfloat162float(xh1[(size_t)(t+1)*16384 + b*512 + 256 + tid]);
    }
    __syncthreads();

    {   // stage 1
        float acc[16];
        float bv = bd0[tid];
#pragma unroll
        for (int r = 0; r < 16; ++r) acc[r] = bv;
        for (int h = 0; h < 256; ++h) {
            float w = Wd0T[h*256 + tid];
#pragma unroll
            for (int r = 0; r < 16; ++r) acc[r] += w * buf0[r][h];
        }
        __syncthreads();
#pragma unroll
        for (int r = 0; r < 16; ++r) buf1[r][tid] = fmaxf(acc[r], 0.0f);
    }
    __syncthreads();

    {   // stage 2
        float acc[16];
        float bv = bd1[tid];
#pragma unroll
        for (int r = 0; r < 16; ++r) acc[r] = bv;
        for (int h = 0; h < 256; ++h) {
            float w = Wd1T[h*256 + tid];
#pragma unroll
            for (int r = 0; r < 16; ++r) acc[r] += w * buf1[r][h];
        }
        __syncthreads();
#pragma unroll
        for (int r = 0; r < 16; ++r) buf0[r][tid] = fmaxf(acc[r], 0.0f);
    }
    __syncthreads();

    {   // stage 3
        const int o = tid & 31;
        const int rr = tid >> 5;
        float a0 = bout[o], a1 = bout[o];
        for (int h = 0; h < 256; ++h) {
            float w = WoutT[h*32 + o];
            a0 += w * buf0[rr*2 + 0][h];
            a1 += w * buf0[rr*2 + 1][h];
        }
        out[(size_t)(row0 + rr*2 + 0)*32 + o] = a0;
        out[(size_t)(row0 + rr*2 + 1)*32 + o] = a1;
    }
}

// ---------------------------------------------------------------------------
extern "C" void kernel_launch(void* const* d_in, const int* in_sizes, int n_in,
                              void* d_out, int out_size, void* d_ws, size_t ws_size,
                              hipStream_t stream) {
    const float* x    = (const float*)d_in[0];
    const float* h0   = (const float*)d_in[1];
    const float* c0   = (const float*)d_in[2];
    const float* Wih0 = (const float*)d_in[3];
    const float* Whh0 = (const float*)d_in[4];
    const float* bih0 = (const float*)d_in[5];
    const float* bhh0 = (const float*)d_in[6];
    const float* Wih1 = (const float*)d_in[7];
    const float* Whh1 = (const float*)d_in[8];
    const float* bih1 = (const float*)d_in[9];
    const float* bhh1 = (const float*)d_in[10];
    const float* Wd0  = (const float*)d_in[11];
    const float* bd0  = (const float*)d_in[12];
    const float* Wd1  = (const float*)d_in[13];
    const float* bd1  = (const float*)d_in[14];
    const float* Wout = (const float*)d_in[15];
    const float* bout = (const float*)d_in[16];

    char* ws = (char*)d_ws;
    float* out = (float*)d_out;

    prep_kernel<<<20344, 256, 0, stream>>>(x, h0, Wih0, Whh0, bih0, bhh0,
                                           Wih1, Whh1, bih1, bhh1,
                                           Wd0, Wd1, Wout, ws);
    lstm_fused<<<32, 512, 0, stream>>>(ws, c0, out);
    head_kernel<<<4096, 256, 0, stream>>>(ws, bd0, bd1, bout, out);
}